// Round 1
// baseline (1299.628 us; speedup 1.0000x reference)
//
#include <hip/hip_runtime.h>
#include <stdint.h>

#define DEVFN __device__ __forceinline__

using f32x4   = __attribute__((ext_vector_type(4)))  float;
using f32x16  = __attribute__((ext_vector_type(16))) float;
using ushort8 = __attribute__((ext_vector_type(8)))  unsigned short;
using bf16x8  = __attribute__((ext_vector_type(8)))  __bf16;

DEVFN unsigned short f2b(float x){
    union { float f; unsigned u; } v; v.f = x;
    unsigned r = v.u + 0x7FFFu + ((v.u >> 16) & 1u);   // RNE
    return (unsigned short)(r >> 16);
}
DEVFN float b2f(unsigned short u){
    union { unsigned u; float f; } v; v.u = ((unsigned)u) << 16; return v.f;
}
DEVFN bf16x8 ld_bf16x8(const unsigned short* p){
    return __builtin_bit_cast(bf16x8, *(const ushort8*)p);
}
DEVFN bf16x8 pack_bf16x8(const float* f){
    ushort8 u;
#pragma unroll
    for (int j = 0; j < 8; ++j) u[j] = f2b(f[j]);
    return __builtin_bit_cast(bf16x8, u);
}
DEVFN f32x16 zero16(){
    f32x16 z;
#pragma unroll
    for (int i = 0; i < 16; ++i) z[i] = 0.f;
    return z;
}
DEVFN f32x16 mfma_bf16(bf16x8 a, bf16x8 b, f32x16 c){
    return __builtin_amdgcn_mfma_f32_32x32x16_bf16(a, b, c, 0, 0, 0);
}

// ---------------- transpose weight [R][Cc] f32 -> [Cc][R] bf16 ----------------
__global__ void k_transpose_bf16(const float* __restrict__ in, unsigned short* __restrict__ out,
                                 int R, int Cc){
    int idx = blockIdx.x * 256 + threadIdx.x;
    if (idx >= R * Cc) return;
    int i = idx / R, j = idx % R;          // out[i][j] = in[j][i]
    out[idx] = f2b(in[(size_t)j * Cc + i]);
}

// ---------------- LN(text) -> bf16 ; one wave per row of 512 ----------------
__global__ __launch_bounds__(256) void k_ln_text(const float* __restrict__ text,
        const float* __restrict__ g, const float* __restrict__ bb,
        unsigned short* __restrict__ out){
    int wave = threadIdx.x >> 6, lane = threadIdx.x & 63;
    size_t row = (size_t)blockIdx.x * 4 + wave;        // 16384 rows
    const float* p = text + row * 512 + lane * 8;
    f32x4 a = *(const f32x4*)p;
    f32x4 c = *(const f32x4*)(p + 4);
    float s = a[0]+a[1]+a[2]+a[3]+c[0]+c[1]+c[2]+c[3];
#pragma unroll
    for (int off = 32; off; off >>= 1) s += __shfl_xor(s, off);
    float mean = s * (1.f/512.f);
    float d[8];
    d[0]=a[0]-mean; d[1]=a[1]-mean; d[2]=a[2]-mean; d[3]=a[3]-mean;
    d[4]=c[0]-mean; d[5]=c[1]-mean; d[6]=c[2]-mean; d[7]=c[3]-mean;
    float vs = d[0]*d[0]+d[1]*d[1]+d[2]*d[2]+d[3]*d[3]+d[4]*d[4]+d[5]*d[5]+d[6]*d[6]+d[7]*d[7];
#pragma unroll
    for (int off = 32; off; off >>= 1) vs += __shfl_xor(vs, off);
    float rstd = rsqrtf(vs * (1.f/512.f) + 1e-5f);
    const float* gp = g  + lane * 8;
    const float* bp = bb + lane * 8;
    f32x4 g0 = *(const f32x4*)gp, g1 = *(const f32x4*)(gp+4);
    f32x4 b0 = *(const f32x4*)bp, b1 = *(const f32x4*)(bp+4);
    ushort8 o;
#pragma unroll
    for (int j = 0; j < 4; ++j) o[j]   = f2b(d[j]  *rstd*g0[j] + b0[j]);
#pragma unroll
    for (int j = 0; j < 4; ++j) o[4+j] = f2b(d[4+j]*rstd*g1[j] + b1[j]);
    *(ushort8*)(out + row * 512 + lane * 8) = o;
}

// ---------------- fused 1x1-conv + adaptive max pool -> xc[b][27][256] ----------------
// Per block: one (scale, batch, bin). D[m=pixel][n=e_out] = sum_c X[c][pix] * W[c][e].
// W^T (bf16, [e][c]) fragments held in registers; max folded over D rows; bias after max.
template<int C, int WIMG, int BINW, int NMT, int NKC>
DEVFN void conv_tile(const float* __restrict__ X, const unsigned short* __restrict__ WT,
                     const float* __restrict__ CB, float* __restrict__ xc,
                     int b, int bin, int sbase){
    const int HW = WIMG * WIMG;
    int tid = threadIdx.x;
    int wave = tid >> 6, lane = tid & 63, lo = lane & 31, hi = lane >> 5;
    int e0 = wave * 64;                         // wave covers 64 output channels (2 n-tiles)
    int binr = bin / 3, binc = bin % 3;
    const float* Xb = X + (size_t)b * C * HW;
    bf16x8 Bf[2][16];
    float rmax0 = -3.4e38f, rmax1 = -3.4e38f;

    auto loadB = [&](int kcbase){
#pragma unroll
        for (int nt = 0; nt < 2; ++nt){
#pragma unroll
            for (int ks = 0; ks < 16; ++ks){
                Bf[nt][ks] = ld_bf16x8(WT + (size_t)(e0 + nt*32 + lo) * C + kcbase + ks*16 + hi*8);
            }
        }
    };
    auto pixrc = [&](int mt, int& gr, int& gc){
        int prow, pcol;
        if constexpr (BINW == 16){ prow = 2*mt + (lo >> 4); pcol = lo & 15; }
        else if constexpr (BINW == 8){ prow = 4*mt + (lo >> 3); pcol = lo & 7; }
        else { prow = (lo & 15) >> 2; pcol = lo & 3; (void)mt; }   // 16 pixels duplicated
        gr = binr * BINW + prow; gc = binc * BINW + pcol;
    };
    auto loadA = [&](int gr, int gc, int cbase) -> bf16x8 {
        const float* p = Xb + (size_t)cbase * HW + gr * WIMG + gc;
        float f[8];
#pragma unroll
        for (int j = 0; j < 8; ++j) f[j] = p[(size_t)j * HW];
        return pack_bf16x8(f);
    };
    auto foldmax = [&](const f32x16& a0, const f32x16& a1){
        float m0 = a0[0], m1 = a1[0];
#pragma unroll
        for (int r = 1; r < 16; ++r){ m0 = fmaxf(m0, a0[r]); m1 = fmaxf(m1, a1[r]); }
        m0 = fmaxf(m0, __shfl_xor(m0, 32));
        m1 = fmaxf(m1, __shfl_xor(m1, 32));
        rmax0 = fmaxf(rmax0, m0); rmax1 = fmaxf(rmax1, m1);
    };

    if constexpr (NKC == 1){
        loadB(0);
#pragma unroll
        for (int mt = 0; mt < NMT; ++mt){
            int gr, gc; pixrc(mt, gr, gc);
            f32x16 a0 = zero16(), a1 = zero16();
#pragma unroll
            for (int ks = 0; ks < 16; ++ks){
                bf16x8 av = loadA(gr, gc, ks*16 + hi*8);
                a0 = mfma_bf16(av, Bf[0][ks], a0);
                a1 = mfma_bf16(av, Bf[1][ks], a1);
            }
            foldmax(a0, a1);
        }
    } else {
        f32x16 acc[NMT][2];
#pragma unroll
        for (int mt = 0; mt < NMT; ++mt){ acc[mt][0] = zero16(); acc[mt][1] = zero16(); }
#pragma unroll
        for (int kc = 0; kc < NKC; ++kc){
            loadB(kc * 256);
#pragma unroll
            for (int mt = 0; mt < NMT; ++mt){
                int gr, gc; pixrc(mt, gr, gc);
#pragma unroll
                for (int ks = 0; ks < 16; ++ks){
                    bf16x8 av = loadA(gr, gc, kc*256 + ks*16 + hi*8);
                    acc[mt][0] = mfma_bf16(av, Bf[0][ks], acc[mt][0]);
                    acc[mt][1] = mfma_bf16(av, Bf[1][ks], acc[mt][1]);
                }
            }
        }
#pragma unroll
        for (int mt = 0; mt < NMT; ++mt) foldmax(acc[mt][0], acc[mt][1]);
    }

    if (lane < 32){
        size_t base = ((size_t)b * 27 + sbase + bin) * 256;
        xc[base + e0 + lo]      = rmax0 + CB[e0 + lo];
        xc[base + e0 + 32 + lo] = rmax1 + CB[e0 + 32 + lo];
    }
}

__global__ __launch_bounds__(256, 2) void k_conv_pool(
        const float* __restrict__ x0, const float* __restrict__ x1, const float* __restrict__ x2,
        const unsigned short* __restrict__ wt0, const unsigned short* __restrict__ wt1,
        const unsigned short* __restrict__ wt2,
        const float* __restrict__ cb0, const float* __restrict__ cb1, const float* __restrict__ cb2,
        float* __restrict__ xc){
    int blk = blockIdx.x;                  // 864 = 3 scales * 32 b * 9 bins
    int s = blk / 288, r = blk % 288, b = r / 9, bin = r % 9;
    if (s == 0)      conv_tile<256, 48, 16, 8, 1>(x0, wt0, cb0, xc, b, bin, 0);
    else if (s == 1) conv_tile<512, 24, 8, 2, 2>(x1, wt1, cb1, xc, b, bin, 9);
    else             conv_tile<1024, 12, 4, 1, 4>(x2, wt2, cb2, xc, b, bin, 18);
}

// ---------------- q = LN(text) @ q_w + q_b  -> bf16 q[row][256] ----------------
__global__ __launch_bounds__(128) void k_qgemm(const unsigned short* __restrict__ lntext,
        const unsigned short* __restrict__ qwt, const float* __restrict__ qb,
        unsigned short* __restrict__ qout){
    int wave = threadIdx.x >> 6, lane = threadIdx.x & 63, lo = lane & 31, hi = lane >> 5;
    size_t row0 = (size_t)blockIdx.x * 64 + wave * 32;
    f32x16 acc[8];
#pragma unroll
    for (int nt = 0; nt < 8; ++nt) acc[nt] = zero16();
    const unsigned short* arow = lntext + (row0 + lo) * 512 + hi * 8;
    for (int ks = 0; ks < 32; ++ks){
        bf16x8 a = ld_bf16x8(arow + ks * 16);
#pragma unroll
        for (int nt = 0; nt < 8; ++nt){
            bf16x8 bfr = ld_bf16x8(qwt + (size_t)(nt*32 + lo) * 512 + ks*16 + hi*8);
            acc[nt] = mfma_bf16(a, bfr, acc[nt]);
        }
    }
#pragma unroll
    for (int nt = 0; nt < 8; ++nt){
        int e = nt * 32 + lo;
        float qbias = qb[e];
#pragma unroll
        for (int r = 0; r < 16; ++r){
            size_t row = row0 + (r & 3) + 8 * (r >> 2) + 4 * hi;
            qout[row * 256 + e] = f2b(acc[nt][r] + qbias);
        }
    }
}

// ---------------- k,v = LN(xc) @ {k_w,v_w} + bias ; 4 rows per block ----------------
__global__ __launch_bounds__(256) void k_kv(const float* __restrict__ xc,
        const float* __restrict__ kg, const float* __restrict__ kb,
        const float* __restrict__ vg, const float* __restrict__ vb,
        const float* __restrict__ k_w, const float* __restrict__ k_bias,
        const float* __restrict__ v_w, const float* __restrict__ v_bias,
        float* __restrict__ kout, float* __restrict__ vout){
    __shared__ float lnk[4][256];
    __shared__ float lnv[4][256];
    int w = threadIdx.x >> 6, lane = threadIdx.x & 63;
    size_t row = (size_t)blockIdx.x * 4 + w;
    f32x4 xv = *(const f32x4*)(xc + row * 256 + lane * 4);
    float s = xv[0]+xv[1]+xv[2]+xv[3];
#pragma unroll
    for (int off = 32; off; off >>= 1) s += __shfl_xor(s, off);
    float mean = s * (1.f/256.f);
    float d0 = xv[0]-mean, d1 = xv[1]-mean, d2 = xv[2]-mean, d3 = xv[3]-mean;
    float vs = d0*d0 + d1*d1 + d2*d2 + d3*d3;
#pragma unroll
    for (int off = 32; off; off >>= 1) vs += __shfl_xor(vs, off);
    float rstd = rsqrtf(vs * (1.f/256.f) + 1e-5f);
    int c0 = lane * 4;
#pragma unroll
    for (int j = 0; j < 4; ++j){
        float dd = xv[j] - mean;
        lnk[w][c0+j] = dd * rstd * kg[c0+j] + kb[c0+j];
        lnv[w][c0+j] = dd * rstd * vg[c0+j] + vb[c0+j];
    }
    __syncthreads();
    int t = threadIdx.x;
    float aK[4], aV[4];
#pragma unroll
    for (int r = 0; r < 4; ++r){ aK[r] = 0.f; aV[r] = 0.f; }
    for (int c = 0; c < 256; ++c){
        float wk = k_w[(size_t)c * 256 + t];
        float wv = v_w[(size_t)c * 256 + t];
#pragma unroll
        for (int r = 0; r < 4; ++r){
            aK[r] += lnk[r][c] * wk;
            aV[r] += lnv[r][c] * wv;
        }
    }
    float kbias = k_bias[t], vbias = v_bias[t];
    size_t base = (size_t)blockIdx.x * 4;
#pragma unroll
    for (int r = 0; r < 4; ++r){
        kout[(base + r) * 256 + t] = aK[r] + kbias;
        vout[(base + r) * 256 + t] = aV[r] + vbias;
    }
}

// ---------------- attention: one block per (b, head); 27 keys in LDS ----------------
__global__ __launch_bounds__(256) void k_attn(const unsigned short* __restrict__ qbf,
        const float* __restrict__ kbuf, const float* __restrict__ vbuf,
        unsigned short* __restrict__ obf){
    int b = blockIdx.x >> 3, h = blockIdx.x & 7;
    __shared__ float ks_[27][32];
    __shared__ float vs_[27][32];
    for (int i = threadIdx.x; i < 27 * 32; i += 256){
        int r = i >> 5, c = i & 31;
        size_t src = ((size_t)b * 27 + r) * 256 + h * 32 + c;
        ks_[r][c] = kbuf[src];
        vs_[r][c] = vbuf[src];
    }
    __syncthreads();
#pragma unroll
    for (int rep = 0; rep < 2; ++rep){
        int n = rep * 256 + threadIdx.x;
        const unsigned short* qp = qbf + ((size_t)b * 512 + n) * 256 + h * 32;
        float q[32];
#pragma unroll
        for (int g4 = 0; g4 < 4; ++g4){
            ushort8 u = *(const ushort8*)(qp + g4 * 8);
#pragma unroll
            for (int j = 0; j < 8; ++j) q[g4*8+j] = b2f(u[j]);
        }
        float sc[27]; float mx = -3.4e38f;
#pragma unroll
        for (int kk = 0; kk < 27; ++kk){
            float s = 0.f;
#pragma unroll
            for (int c = 0; c < 32; ++c) s += q[c] * ks_[kk][c];
            s *= 0.17677669529663687f;           // 1/sqrt(32)
            sc[kk] = s; mx = fmaxf(mx, s);
        }
        float sum = 0.f;
#pragma unroll
        for (int kk = 0; kk < 27; ++kk){ float p = __expf(sc[kk] - mx); sc[kk] = p; sum += p; }
        float inv = 1.f / sum;
        float o[32];
#pragma unroll
        for (int c = 0; c < 32; ++c) o[c] = 0.f;
#pragma unroll
        for (int kk = 0; kk < 27; ++kk){
            float p = sc[kk] * inv;
#pragma unroll
            for (int c = 0; c < 32; ++c) o[c] += p * vs_[kk][c];
        }
        unsigned short* op = obf + ((size_t)b * 512 + n) * 256 + h * 32;
#pragma unroll
        for (int g4 = 0; g4 < 4; ++g4){
            ushort8 u;
#pragma unroll
            for (int j = 0; j < 8; ++j) u[j] = f2b(o[g4*8+j]);
            *(ushort8*)(op + g4 * 8) = u;
        }
    }
}

// ---------------- out = O @ proj_w + proj_b + text ----------------
__global__ __launch_bounds__(128) void k_proj(const unsigned short* __restrict__ obf,
        const unsigned short* __restrict__ pwt, const float* __restrict__ pb,
        const float* __restrict__ text, float* __restrict__ out){
    int wave = threadIdx.x >> 6, lane = threadIdx.x & 63, lo = lane & 31, hi = lane >> 5;
    size_t row0 = (size_t)(blockIdx.x >> 1) * 64 + wave * 32;
    int ct0 = (blockIdx.x & 1) * 256;
    f32x16 acc[8];
#pragma unroll
    for (int nt = 0; nt < 8; ++nt) acc[nt] = zero16();
    const unsigned short* arow = obf + (row0 + lo) * 256 + hi * 8;
    for (int ks = 0; ks < 16; ++ks){
        bf16x8 a = ld_bf16x8(arow + ks * 16);
#pragma unroll
        for (int nt = 0; nt < 8; ++nt){
            bf16x8 bfr = ld_bf16x8(pwt + (size_t)(ct0 + nt*32 + lo) * 256 + ks*16 + hi*8);
            acc[nt] = mfma_bf16(a, bfr, acc[nt]);
        }
    }
#pragma unroll
    for (int nt = 0; nt < 8; ++nt){
        int ct = ct0 + nt * 32 + lo;
        float pbias = pb[ct];
#pragma unroll
        for (int r = 0; r < 16; ++r){
            size_t row = row0 + (r & 3) + 8 * (r >> 2) + 4 * hi;
            out[row * 512 + ct] = acc[nt][r] + pbias + text[row * 512 + ct];
        }
    }
}

extern "C" void kernel_launch(void* const* d_in, const int* in_sizes, int n_in,
                              void* d_out, int out_size, void* d_ws, size_t ws_size,
                              hipStream_t stream) {
    (void)in_sizes; (void)n_in; (void)out_size; (void)ws_size;
    const float* x0     = (const float*)d_in[0];
    const float* x1     = (const float*)d_in[1];
    const float* x2     = (const float*)d_in[2];
    const float* text   = (const float*)d_in[3];
    const float* w0     = (const float*)d_in[4];
    const float* cb0    = (const float*)d_in[5];
    const float* w1     = (const float*)d_in[6];
    const float* cb1    = (const float*)d_in[7];
    const float* w2     = (const float*)d_in[8];
    const float* cb2    = (const float*)d_in[9];
    const float* q_ln_g = (const float*)d_in[10];
    const float* q_ln_b = (const float*)d_in[11];
    const float* k_ln_g = (const float*)d_in[12];
    const float* k_ln_b = (const float*)d_in[13];
    const float* v_ln_g = (const float*)d_in[14];
    const float* v_ln_b = (const float*)d_in[15];
    const float* q_w    = (const float*)d_in[16];
    const float* q_b    = (const float*)d_in[17];
    const float* k_w    = (const float*)d_in[18];
    const float* k_b    = (const float*)d_in[19];
    const float* v_w    = (const float*)d_in[20];
    const float* v_b    = (const float*)d_in[21];
    const float* proj_w = (const float*)d_in[22];
    const float* proj_b = (const float*)d_in[23];
    float* out = (float*)d_out;

    char* wsb = (char*)d_ws; size_t off = 0;
    auto take = [&](size_t bytes) -> void* {
        void* p = wsb + off; off += (bytes + 255) & ~(size_t)255; return p;
    };
    unsigned short* lntext = (unsigned short*)take((size_t)16384 * 512 * 2);
    unsigned short* qbf    = (unsigned short*)take((size_t)16384 * 256 * 2);
    unsigned short* obf    = (unsigned short*)take((size_t)16384 * 256 * 2);
    float*          xc     = (float*)take((size_t)32 * 27 * 256 * 4);
    float*          kbuf   = (float*)take((size_t)32 * 27 * 256 * 4);
    float*          vbuf   = (float*)take((size_t)32 * 27 * 256 * 4);
    unsigned short* wt0    = (unsigned short*)take((size_t)256 * 256 * 2);
    unsigned short* wt1    = (unsigned short*)take((size_t)256 * 512 * 2);
    unsigned short* wt2    = (unsigned short*)take((size_t)256 * 1024 * 2);
    unsigned short* qwt    = (unsigned short*)take((size_t)256 * 512 * 2);
    unsigned short* pwt    = (unsigned short*)take((size_t)512 * 256 * 2);

    k_transpose_bf16<<<(256*256 + 255) / 256, 256, 0, stream>>>(w0, wt0, 256, 256);
    k_transpose_bf16<<<(512*256 + 255) / 256, 256, 0, stream>>>(w1, wt1, 512, 256);
    k_transpose_bf16<<<(1024*256 + 255) / 256, 256, 0, stream>>>(w2, wt2, 1024, 256);
    k_transpose_bf16<<<(512*256 + 255) / 256, 256, 0, stream>>>(q_w, qwt, 512, 256);
    k_transpose_bf16<<<(256*512 + 255) / 256, 256, 0, stream>>>(proj_w, pwt, 256, 512);

    k_ln_text<<<4096, 256, 0, stream>>>(text, q_ln_g, q_ln_b, lntext);
    k_conv_pool<<<864, 256, 0, stream>>>(x0, x1, x2, wt0, wt1, wt2, cb0, cb1, cb2, xc);
    k_qgemm<<<256, 128, 0, stream>>>(lntext, qwt, q_b, qbf);
    k_kv<<<216, 256, 0, stream>>>(xc, k_ln_g, k_ln_b, v_ln_g, v_ln_b,
                                  k_w, k_b, v_w, v_b, kbuf, vbuf);
    k_attn<<<256, 256, 0, stream>>>(qbf, kbuf, vbuf, obf);
    k_proj<<<512, 128, 0, stream>>>(obf, pwt, proj_b, text, out);
}

// Round 3
// 739.600 us; speedup vs baseline: 1.7572x; 1.7572x over previous
//
#include <hip/hip_runtime.h>
#include <stdint.h>

#define DEVFN __device__ __forceinline__

using f32x4   = __attribute__((ext_vector_type(4)))  float;
using f32x16  = __attribute__((ext_vector_type(16))) float;
using us4     = __attribute__((ext_vector_type(4)))  unsigned short;
using us8     = __attribute__((ext_vector_type(8)))  unsigned short;
using bf16x8  = __attribute__((ext_vector_type(8)))  __bf16;

DEVFN unsigned short f2b(float x){
    union { float f; unsigned u; } v; v.f = x;
    unsigned r = v.u + 0x7FFFu + ((v.u >> 16) & 1u);   // RNE
    return (unsigned short)(r >> 16);
}
DEVFN float b2f(unsigned short u){
    union { unsigned u; float f; } v; v.u = ((unsigned)u) << 16; return v.f;
}
DEVFN bf16x8 ld_bf16x8(const unsigned short* p){
    return __builtin_bit_cast(bf16x8, *(const us8*)p);
}
DEVFN bf16x8 pack_bf16x8(const float* f){
    us8 u;
#pragma unroll
    for (int j = 0; j < 8; ++j) u[j] = f2b(f[j]);
    return __builtin_bit_cast(bf16x8, u);
}
DEVFN f32x16 zero16(){
    f32x16 z;
#pragma unroll
    for (int i = 0; i < 16; ++i) z[i] = 0.f;
    return z;
}
DEVFN f32x16 mfma_bf16(bf16x8 a, bf16x8 b, f32x16 c){
    return __builtin_amdgcn_mfma_f32_32x32x16_bf16(a, b, c, 0, 0, 0);
}

// ---------------- transpose weight [R][Cc] f32 -> [Cc][R] bf16 ----------------
__global__ void k_transpose_bf16(const float* __restrict__ in, unsigned short* __restrict__ out,
                                 int R, int Cc){
    int idx = blockIdx.x * 256 + threadIdx.x;
    if (idx >= R * Cc) return;
    int i = idx / R, j = idx % R;          // out[i][j] = in[j][i]
    out[idx] = f2b(in[(size_t)j * Cc + i]);
}

// ---------------- LN(text) -> bf16 ; one wave per row of 512 ----------------
__global__ __launch_bounds__(256) void k_ln_text(const float* __restrict__ text,
        const float* __restrict__ g, const float* __restrict__ bb,
        unsigned short* __restrict__ out){
    int wave = threadIdx.x >> 6, lane = threadIdx.x & 63;
    size_t row = (size_t)blockIdx.x * 4 + wave;        // 16384 rows
    const float* p = text + row * 512 + lane * 8;
    f32x4 a = *(const f32x4*)p;
    f32x4 c = *(const f32x4*)(p + 4);
    float s = a[0]+a[1]+a[2]+a[3]+c[0]+c[1]+c[2]+c[3];
#pragma unroll
    for (int off = 32; off; off >>= 1) s += __shfl_xor(s, off);
    float mean = s * (1.f/512.f);
    float d[8];
    d[0]=a[0]-mean; d[1]=a[1]-mean; d[2]=a[2]-mean; d[3]=a[3]-mean;
    d[4]=c[0]-mean; d[5]=c[1]-mean; d[6]=c[2]-mean; d[7]=c[3]-mean;
    float vs = d[0]*d[0]+d[1]*d[1]+d[2]*d[2]+d[3]*d[3]+d[4]*d[4]+d[5]*d[5]+d[6]*d[6]+d[7]*d[7];
#pragma unroll
    for (int off = 32; off; off >>= 1) vs += __shfl_xor(vs, off);
    float rstd = rsqrtf(vs * (1.f/512.f) + 1e-5f);
    const float* gp = g  + lane * 8;
    const float* bp = bb + lane * 8;
    f32x4 g0 = *(const f32x4*)gp, g1 = *(const f32x4*)(gp+4);
    f32x4 b0 = *(const f32x4*)bp, b1 = *(const f32x4*)(bp+4);
    us8 o;
#pragma unroll
    for (int j = 0; j < 4; ++j) o[j]   = f2b(d[j]  *rstd*g0[j] + b0[j]);
#pragma unroll
    for (int j = 0; j < 4; ++j) o[4+j] = f2b(d[4+j]*rstd*g1[j] + b1[j]);
    *(us8*)(out + row * 512 + lane * 8) = o;
}

// ---------------- fused 1x1-conv + adaptive max pool -> xc[b][27][256] ----------------
template<int C, int WIMG, int BINW, int NMT, int NKC>
DEVFN void conv_tile(const float* __restrict__ X, const unsigned short* __restrict__ WT,
                     const float* __restrict__ CB, float* __restrict__ xc,
                     int b, int bin, int sbase){
    const int HW = WIMG * WIMG;
    int tid = threadIdx.x;
    int wave = tid >> 6, lane = tid & 63, lo = lane & 31, hi = lane >> 5;
    int e0 = wave * 64;                         // wave covers 64 output channels (2 n-tiles)
    int binr = bin / 3, binc = bin % 3;
    const float* Xb = X + (size_t)b * C * HW;
    bf16x8 Bf[2][16];
    float rmax0 = -3.4e38f, rmax1 = -3.4e38f;

    auto loadB = [&](int kcbase){
#pragma unroll
        for (int nt = 0; nt < 2; ++nt){
#pragma unroll
            for (int ks = 0; ks < 16; ++ks){
                Bf[nt][ks] = ld_bf16x8(WT + (size_t)(e0 + nt*32 + lo) * C + kcbase + ks*16 + hi*8);
            }
        }
    };
    auto pixrc = [&](int mt, int& gr, int& gc){
        int prow, pcol;
        if constexpr (BINW == 16){ prow = 2*mt + (lo >> 4); pcol = lo & 15; }
        else if constexpr (BINW == 8){ prow = 4*mt + (lo >> 3); pcol = lo & 7; }
        else { prow = (lo & 15) >> 2; pcol = lo & 3; (void)mt; }   // 16 pixels duplicated
        gr = binr * BINW + prow; gc = binc * BINW + pcol;
    };
    auto loadA = [&](int gr, int gc, int cbase) -> bf16x8 {
        const float* p = Xb + (size_t)cbase * HW + gr * WIMG + gc;
        float f[8];
#pragma unroll
        for (int j = 0; j < 8; ++j) f[j] = p[(size_t)j * HW];
        return pack_bf16x8(f);
    };
    auto foldmax = [&](const f32x16& a0, const f32x16& a1){
        float m0 = a0[0], m1 = a1[0];
#pragma unroll
        for (int r = 1; r < 16; ++r){ m0 = fmaxf(m0, a0[r]); m1 = fmaxf(m1, a1[r]); }
        m0 = fmaxf(m0, __shfl_xor(m0, 32));
        m1 = fmaxf(m1, __shfl_xor(m1, 32));
        rmax0 = fmaxf(rmax0, m0); rmax1 = fmaxf(rmax1, m1);
    };

    if constexpr (NKC == 1){
        loadB(0);
#pragma unroll
        for (int mt = 0; mt < NMT; ++mt){
            int gr, gc; pixrc(mt, gr, gc);
            f32x16 a0 = zero16(), a1 = zero16();
#pragma unroll
            for (int ks = 0; ks < 16; ++ks){
                bf16x8 av = loadA(gr, gc, ks*16 + hi*8);
                a0 = mfma_bf16(av, Bf[0][ks], a0);
                a1 = mfma_bf16(av, Bf[1][ks], a1);
            }
            foldmax(a0, a1);
        }
    } else {
        f32x16 acc[NMT][2];
#pragma unroll
        for (int mt = 0; mt < NMT; ++mt){ acc[mt][0] = zero16(); acc[mt][1] = zero16(); }
#pragma unroll
        for (int kc = 0; kc < NKC; ++kc){
            loadB(kc * 256);
#pragma unroll
            for (int mt = 0; mt < NMT; ++mt){
                int gr, gc; pixrc(mt, gr, gc);
#pragma unroll
                for (int ks = 0; ks < 16; ++ks){
                    bf16x8 av = loadA(gr, gc, kc*256 + ks*16 + hi*8);
                    acc[mt][0] = mfma_bf16(av, Bf[0][ks], acc[mt][0]);
                    acc[mt][1] = mfma_bf16(av, Bf[1][ks], acc[mt][1]);
                }
            }
        }
#pragma unroll
        for (int mt = 0; mt < NMT; ++mt) foldmax(acc[mt][0], acc[mt][1]);
    }

    if (lane < 32){
        size_t base = ((size_t)b * 27 + sbase + bin) * 256;
        xc[base + e0 + lo]      = rmax0 + CB[e0 + lo];
        xc[base + e0 + 32 + lo] = rmax1 + CB[e0 + 32 + lo];
    }
}

__global__ __launch_bounds__(256, 2) void k_conv_pool(
        const float* __restrict__ x0, const float* __restrict__ x1, const float* __restrict__ x2,
        const unsigned short* __restrict__ wt0, const unsigned short* __restrict__ wt1,
        const unsigned short* __restrict__ wt2,
        const float* __restrict__ cb0, const float* __restrict__ cb1, const float* __restrict__ cb2,
        float* __restrict__ xc){
    int blk = blockIdx.x;                  // 864 = 3 scales * 32 b * 9 bins
    int s = blk / 288, r = blk % 288, b = r / 9, bin = r % 9;
    if (s == 0)      conv_tile<256, 48, 16, 8, 1>(x0, wt0, cb0, xc, b, bin, 0);
    else if (s == 1) conv_tile<512, 24, 8, 2, 2>(x1, wt1, cb1, xc, b, bin, 9);
    else             conv_tile<1024, 12, 4, 1, 4>(x2, wt2, cb2, xc, b, bin, 18);
}

// ---------------- q = LN(text) @ q_w + q_b  -> bf16 q[row][256] ----------------
__global__ __launch_bounds__(128) void k_qgemm(const unsigned short* __restrict__ lntext,
        const unsigned short* __restrict__ qwt, const float* __restrict__ qb,
        unsigned short* __restrict__ qout){
    int wave = threadIdx.x >> 6, lane = threadIdx.x & 63, lo = lane & 31, hi = lane >> 5;
    size_t row0 = (size_t)blockIdx.x * 64 + wave * 32;
    f32x16 acc[8];
#pragma unroll
    for (int nt = 0; nt < 8; ++nt) acc[nt] = zero16();
    const unsigned short* arow = lntext + (row0 + lo) * 512 + hi * 8;
    for (int ks = 0; ks < 32; ++ks){
        bf16x8 a = ld_bf16x8(arow + ks * 16);
#pragma unroll
        for (int nt = 0; nt < 8; ++nt){
            bf16x8 bfr = ld_bf16x8(qwt + (size_t)(nt*32 + lo) * 512 + ks*16 + hi*8);
            acc[nt] = mfma_bf16(a, bfr, acc[nt]);
        }
    }
#pragma unroll
    for (int nt = 0; nt < 8; ++nt){
        int e = nt * 32 + lo;
        float qbias = qb[e];
#pragma unroll
        for (int r = 0; r < 16; ++r){
            size_t row = row0 + (r & 3) + 8 * (r >> 2) + 4 * hi;
            qout[row * 256 + e] = f2b(acc[nt][r] + qbias);
        }
    }
}

// ---------------- k,v = LN(xc) @ {k_w,v_w} + bias ; 4 rows per block ----------------
__global__ __launch_bounds__(256) void k_kv(const float* __restrict__ xc,
        const float* __restrict__ kg, const float* __restrict__ kb,
        const float* __restrict__ vg, const float* __restrict__ vb,
        const float* __restrict__ k_w, const float* __restrict__ k_bias,
        const float* __restrict__ v_w, const float* __restrict__ v_bias,
        float* __restrict__ kout, float* __restrict__ vout){
    __shared__ float lnk[4][256];
    __shared__ float lnv[4][256];
    int w = threadIdx.x >> 6, lane = threadIdx.x & 63;
    size_t row = (size_t)blockIdx.x * 4 + w;
    f32x4 xv = *(const f32x4*)(xc + row * 256 + lane * 4);
    float s = xv[0]+xv[1]+xv[2]+xv[3];
#pragma unroll
    for (int off = 32; off; off >>= 1) s += __shfl_xor(s, off);
    float mean = s * (1.f/256.f);
    float d0 = xv[0]-mean, d1 = xv[1]-mean, d2 = xv[2]-mean, d3 = xv[3]-mean;
    float vs = d0*d0 + d1*d1 + d2*d2 + d3*d3;
#pragma unroll
    for (int off = 32; off; off >>= 1) vs += __shfl_xor(vs, off);
    float rstd = rsqrtf(vs * (1.f/256.f) + 1e-5f);
    int c0 = lane * 4;
#pragma unroll
    for (int j = 0; j < 4; ++j){
        float dd = xv[j] - mean;
        lnk[w][c0+j] = dd * rstd * kg[c0+j] + kb[c0+j];
        lnv[w][c0+j] = dd * rstd * vg[c0+j] + vb[c0+j];
    }
    __syncthreads();
    int t = threadIdx.x;
    float aK[4], aV[4];
#pragma unroll
    for (int r = 0; r < 4; ++r){ aK[r] = 0.f; aV[r] = 0.f; }
    for (int c = 0; c < 256; ++c){
        float wk = k_w[(size_t)c * 256 + t];
        float wv = v_w[(size_t)c * 256 + t];
#pragma unroll
        for (int r = 0; r < 4; ++r){
            aK[r] += lnk[r][c] * wk;
            aV[r] += lnv[r][c] * wv;
        }
    }
    float kbias = k_bias[t], vbias = v_bias[t];
    size_t base = (size_t)blockIdx.x * 4;
#pragma unroll
    for (int r = 0; r < 4; ++r){
        kout[(base + r) * 256 + t] = aK[r] + kbias;
        vout[(base + r) * 256 + t] = aV[r] + vbias;
    }
}

// ---------------- attention: block = (b, row-group of 32); lane owns 4 channels ----------------
// head h = channels 32h..32h+31 = lanes 8h..8h+7 (4 ch each); score reduce = shfl_xor 1,2,4.
__global__ __launch_bounds__(256, 2) void k_attn(const unsigned short* __restrict__ qbf,
        const float* __restrict__ kbuf, const float* __restrict__ vbuf,
        unsigned short* __restrict__ obf){
    int b = blockIdx.x >> 4;           // 32 batches
    int rg = blockIdx.x & 15;          // 16 row-groups of 32 rows
    __shared__ float ks_[27 * 256];
    __shared__ float vs_[27 * 256];
    {
        const f32x4* ksrc = (const f32x4*)(kbuf + (size_t)b * 27 * 256);
        const f32x4* vsrc = (const f32x4*)(vbuf + (size_t)b * 27 * 256);
        f32x4* kd = (f32x4*)ks_;
        f32x4* vd = (f32x4*)vs_;
        for (int i = threadIdx.x; i < 27 * 64; i += 256){ kd[i] = ksrc[i]; vd[i] = vsrc[i]; }
    }
    __syncthreads();
    int wave = threadIdx.x >> 6, lane = threadIdx.x & 63;
    int c0 = lane * 4;                 // 4 channels per lane; 256 channels per row
#pragma unroll
    for (int rr = 0; rr < 8; ++rr){
        int row = rg * 32 + wave * 8 + rr;
        const unsigned short* qp = qbf + ((size_t)b * 512 + row) * 256 + c0;
        us4 qu = *(const us4*)qp;
        float q0 = b2f(qu[0]), q1 = b2f(qu[1]), q2 = b2f(qu[2]), q3 = b2f(qu[3]);
        float sc[27]; float mx = -3.4e38f;
#pragma unroll
        for (int kk = 0; kk < 27; ++kk){
            f32x4 kv = *(const f32x4*)(ks_ + kk * 256 + c0);
            float s = q0*kv[0] + q1*kv[1] + q2*kv[2] + q3*kv[3];
            s += __shfl_xor(s, 1); s += __shfl_xor(s, 2); s += __shfl_xor(s, 4);
            s *= 0.17677669529663687f;            // 1/sqrt(32)
            sc[kk] = s; mx = fmaxf(mx, s);
        }
        float sum = 0.f;
#pragma unroll
        for (int kk = 0; kk < 27; ++kk){ float p = __expf(sc[kk] - mx); sc[kk] = p; sum += p; }
        float inv = 1.f / sum;
        float o0 = 0.f, o1 = 0.f, o2 = 0.f, o3 = 0.f;
#pragma unroll
        for (int kk = 0; kk < 27; ++kk){
            f32x4 vv = *(const f32x4*)(vs_ + kk * 256 + c0);
            float p = sc[kk];
            o0 += p*vv[0]; o1 += p*vv[1]; o2 += p*vv[2]; o3 += p*vv[3];
        }
        us4 ou;
        ou[0] = f2b(o0*inv); ou[1] = f2b(o1*inv); ou[2] = f2b(o2*inv); ou[3] = f2b(o3*inv);
        *(us4*)(obf + ((size_t)b * 512 + row) * 256 + c0) = ou;
    }
}

// ---------------- out = O @ proj_w + proj_b + text ----------------
__global__ __launch_bounds__(128) void k_proj(const unsigned short* __restrict__ obf,
        const unsigned short* __restrict__ pwt, const float* __restrict__ pb,
        const float* __restrict__ text, float* __restrict__ out){
    int wave = threadIdx.x >> 6, lane = threadIdx.x & 63, lo = lane & 31, hi = lane >> 5;
    size_t row0 = (size_t)(blockIdx.x >> 1) * 64 + wave * 32;
    int ct0 = (blockIdx.x & 1) * 256;
    f32x16 acc[8];
#pragma unroll
    for (int nt = 0; nt < 8; ++nt) acc[nt] = zero16();
    const unsigned short* arow = obf + (row0 + lo) * 256 + hi * 8;
    for (int ks = 0; ks < 16; ++ks){
        bf16x8 a = ld_bf16x8(arow + ks * 16);
#pragma unroll
        for (int nt = 0; nt < 8; ++nt){
            bf16x8 bfr = ld_bf16x8(pwt + (size_t)(ct0 + nt*32 + lo) * 256 + ks*16 + hi*8);
            acc[nt] = mfma_bf16(a, bfr, acc[nt]);
        }
    }
#pragma unroll
    for (int nt = 0; nt < 8; ++nt){
        int ct = ct0 + nt * 32 + lo;
        float pbias = pb[ct];
#pragma unroll
        for (int r = 0; r < 16; ++r){
            size_t row = row0 + (r & 3) + 8 * (r >> 2) + 4 * hi;
            out[row * 512 + ct] = acc[nt][r] + pbias + text[row * 512 + ct];
        }
    }
}

extern "C" void kernel_launch(void* const* d_in, const int* in_sizes, int n_in,
                              void* d_out, int out_size, void* d_ws, size_t ws_size,
                              hipStream_t stream) {
    (void)in_sizes; (void)n_in; (void)out_size; (void)ws_size;
    const float* x0     = (const float*)d_in[0];
    const float* x1     = (const float*)d_in[1];
    const float* x2     = (const float*)d_in[2];
    const float* text   = (const float*)d_in[3];
    const float* w0     = (const float*)d_in[4];
    const float* cb0    = (const float*)d_in[5];
    const float* w1     = (const float*)d_in[6];
    const float* cb1    = (const float*)d_in[7];
    const float* w2     = (const float*)d_in[8];
    const float* cb2    = (const float*)d_in[9];
    const float* q_ln_g = (const float*)d_in[10];
    const float* q_ln_b = (const float*)d_in[11];
    const float* k_ln_g = (const float*)d_in[12];
    const float* k_ln_b = (const float*)d_in[13];
    const float* v_ln_g = (const float*)d_in[14];
    const float* v_ln_b = (const float*)d_in[15];
    const float* q_w    = (const float*)d_in[16];
    const float* q_b    = (const float*)d_in[17];
    const float* k_w    = (const float*)d_in[18];
    const float* k_b    = (const float*)d_in[19];
    const float* v_w    = (const float*)d_in[20];
    const float* v_b    = (const float*)d_in[21];
    const float* proj_w = (const float*)d_in[22];
    const float* proj_b = (const float*)d_in[23];
    float* out = (float*)d_out;

    char* wsb = (char*)d_ws; size_t off = 0;
    auto take = [&](size_t bytes) -> void* {
        void* p = wsb + off; off += (bytes + 255) & ~(size_t)255; return p;
    };
    unsigned short* lntext = (unsigned short*)take((size_t)16384 * 512 * 2);
    unsigned short* qbf    = (unsigned short*)take((size_t)16384 * 256 * 2);
    unsigned short* obf    = (unsigned short*)take((size_t)16384 * 256 * 2);
    float*          xc     = (float*)take((size_t)32 * 27 * 256 * 4);
    float*          kbuf   = (float*)take((size_t)32 * 27 * 256 * 4);
    float*          vbuf   = (float*)take((size_t)32 * 27 * 256 * 4);
    unsigned short* wt0    = (unsigned short*)take((size_t)256 * 256 * 2);
    unsigned short* wt1    = (unsigned short*)take((size_t)256 * 512 * 2);
    unsigned short* wt2    = (unsigned short*)take((size_t)256 * 1024 * 2);
    unsigned short* qwt    = (unsigned short*)take((size_t)256 * 512 * 2);
    unsigned short* pwt    = (unsigned short*)take((size_t)512 * 256 * 2);

    k_transpose_bf16<<<(256*256 + 255) / 256, 256, 0, stream>>>(w0, wt0, 256, 256);
    k_transpose_bf16<<<(512*256 + 255) / 256, 256, 0, stream>>>(w1, wt1, 512, 256);
    k_transpose_bf16<<<(1024*256 + 255) / 256, 256, 0, stream>>>(w2, wt2, 1024, 256);
    k_transpose_bf16<<<(512*256 + 255) / 256, 256, 0, stream>>>(q_w, qwt, 512, 256);
    k_transpose_bf16<<<(256*512 + 255) / 256, 256, 0, stream>>>(proj_w, pwt, 256, 512);

    k_ln_text<<<4096, 256, 0, stream>>>(text, q_ln_g, q_ln_b, lntext);
    k_conv_pool<<<864, 256, 0, stream>>>(x0, x1, x2, wt0, wt1, wt2, cb0, cb1, cb2, xc);
    k_qgemm<<<256, 128, 0, stream>>>(lntext, qwt, q_b, qbf);
    k_kv<<<216, 256, 0, stream>>>(xc, k_ln_g, k_ln_b, v_ln_g, v_ln_b,
                                  k_w, k_b, v_w, v_b, kbuf, vbuf);
    k_attn<<<512, 256, 0, stream>>>(qbf, kbuf, vbuf, obf);
    k_proj<<<512, 128, 0, stream>>>(obf, pwt, proj_b, text, out);
}

// Round 5
// 368.935 us; speedup vs baseline: 3.5226x; 2.0047x over previous
//
#include <hip/hip_runtime.h>
#include <stdint.h>

#define DEVFN __device__ __forceinline__

using f32x4   = __attribute__((ext_vector_type(4)))  float;
using f32x16  = __attribute__((ext_vector_type(16))) float;
using us4     = __attribute__((ext_vector_type(4)))  unsigned short;
using us8     = __attribute__((ext_vector_type(8)))  unsigned short;
using bf16x8  = __attribute__((ext_vector_type(8)))  __bf16;

DEVFN unsigned short f2b(float x){
    union { float f; unsigned u; } v; v.f = x;
    unsigned r = v.u + 0x7FFFu + ((v.u >> 16) & 1u);   // RNE
    return (unsigned short)(r >> 16);
}
DEVFN float b2f(unsigned short u){
    union { unsigned u; float f; } v; v.u = ((unsigned)u) << 16; return v.f;
}
DEVFN bf16x8 ld_bf16x8(const unsigned short* p){
    return __builtin_bit_cast(bf16x8, *(const us8*)p);
}
DEVFN bf16x8 pack_bf16x8(const float* f){
    us8 u;
#pragma unroll
    for (int j = 0; j < 8; ++j) u[j] = f2b(f[j]);
    return __builtin_bit_cast(bf16x8, u);
}
DEVFN f32x16 zero16(){
    f32x16 z;
#pragma unroll
    for (int i = 0; i < 16; ++i) z[i] = 0.f;
    return z;
}
DEVFN f32x16 mfma_bf16(bf16x8 a, bf16x8 b, f32x16 c){
    return __builtin_amdgcn_mfma_f32_32x32x16_bf16(a, b, c, 0, 0, 0);
}

// ---------------- transpose weight [R][Cc] f32 -> [Cc][R] bf16 ----------------
__global__ void k_transpose_bf16(const float* __restrict__ in, unsigned short* __restrict__ out,
                                 int R, int Cc){
    int idx = blockIdx.x * 256 + threadIdx.x;
    if (idx >= R * Cc) return;
    int i = idx / R, j = idx % R;          // out[i][j] = in[j][i]
    out[idx] = f2b(in[(size_t)j * Cc + i]);
}

// ---------------- LN(text) -> bf16 ; one wave per row of 512 ----------------
__global__ __launch_bounds__(256) void k_ln_text(const float* __restrict__ text,
        const float* __restrict__ g, const float* __restrict__ bb,
        unsigned short* __restrict__ out){
    int wave = threadIdx.x >> 6, lane = threadIdx.x & 63;
    size_t row = (size_t)blockIdx.x * 4 + wave;        // 16384 rows
    const float* p = text + row * 512 + lane * 8;
    f32x4 a = *(const f32x4*)p;
    f32x4 c = *(const f32x4*)(p + 4);
    float s = a[0]+a[1]+a[2]+a[3]+c[0]+c[1]+c[2]+c[3];
#pragma unroll
    for (int off = 32; off; off >>= 1) s += __shfl_xor(s, off);
    float mean = s * (1.f/512.f);
    float d[8];
    d[0]=a[0]-mean; d[1]=a[1]-mean; d[2]=a[2]-mean; d[3]=a[3]-mean;
    d[4]=c[0]-mean; d[5]=c[1]-mean; d[6]=c[2]-mean; d[7]=c[3]-mean;
    float vs = d[0]*d[0]+d[1]*d[1]+d[2]*d[2]+d[3]*d[3]+d[4]*d[4]+d[5]*d[5]+d[6]*d[6]+d[7]*d[7];
#pragma unroll
    for (int off = 32; off; off >>= 1) vs += __shfl_xor(vs, off);
    float rstd = rsqrtf(vs * (1.f/512.f) + 1e-5f);
    const float* gp = g  + lane * 8;
    const float* bp = bb + lane * 8;
    f32x4 g0 = *(const f32x4*)gp, g1 = *(const f32x4*)(gp+4);
    f32x4 b0 = *(const f32x4*)bp, b1 = *(const f32x4*)(bp+4);
    us8 o;
#pragma unroll
    for (int j = 0; j < 4; ++j) o[j]   = f2b(d[j]  *rstd*g0[j] + b0[j]);
#pragma unroll
    for (int j = 0; j < 4; ++j) o[4+j] = f2b(d[4+j]*rstd*g1[j] + b1[j]);
    *(us8*)(out + row * 512 + lane * 8) = o;
}

// ---------------- fused 1x1-conv + adaptive max pool -> xc[b][27][256] ----------------
// One WAVE owns one bin entirely: loops NSUB 32-pixel sub-tiles serially,
// acc[8] reset per sub-tile, per-sub max folded into rmax[8] scalars.
// W fragments transient (16B L2-hot loads) -> no spill, no cross-wave races.
template<int C, int WIMG, int BINW, int SBASE, int NSUB>
DEVFN void conv_bin(const float* __restrict__ X, const unsigned short* __restrict__ WT,
                    const float* __restrict__ CB, float* __restrict__ xc,
                    int b, int bin){
    const int HW = WIMG * WIMG;
    int lane = threadIdx.x & 63, lo = lane & 31, hi = lane >> 5;
    int binr = bin / 3, binc = bin % 3;
    const float* Xb = X + (size_t)b * C * HW;
    const unsigned short* wbase = WT + (size_t)lo * C + hi * 8;  // + nt*32*C + ks*16

    float rmax[8];
#pragma unroll
    for (int nt = 0; nt < 8; ++nt) rmax[nt] = -3.4e38f;

    for (int sub = 0; sub < NSUB; ++sub){
        int prow, pcol;
        if constexpr (BINW == 16){ prow = sub*2 + (lo>>4); pcol = lo & 15; }
        else if constexpr (BINW == 8){ prow = sub*4 + (lo>>3); pcol = lo & 7; }
        else { prow = (lo & 15) >> 2; pcol = lo & 3; }     // 16 px duplicated x2
        int gr = binr * BINW + prow, gc = binc * BINW + pcol;
        const float* Xp = Xb + gr * WIMG + gc;

        f32x16 acc[8];
#pragma unroll
        for (int nt = 0; nt < 8; ++nt) acc[nt] = zero16();

        for (int ks = 0; ks < C/16; ++ks){
            const float* ap = Xp + (size_t)(ks*16 + hi*8) * HW;
            float f[8];
#pragma unroll
            for (int j = 0; j < 8; ++j) f[j] = ap[(size_t)j * HW];
            bf16x8 A = pack_bf16x8(f);
#pragma unroll
            for (int nt = 0; nt < 8; ++nt){
                bf16x8 B = ld_bf16x8(wbase + (size_t)nt*32*C + ks*16);
                acc[nt] = mfma_bf16(A, B, acc[nt]);
            }
        }
#pragma unroll
        for (int nt = 0; nt < 8; ++nt){
            float m = acc[nt][0];
#pragma unroll
            for (int r = 1; r < 16; ++r) m = fmaxf(m, acc[nt][r]);
            rmax[nt] = fmaxf(rmax[nt], m);
        }
    }
#pragma unroll
    for (int nt = 0; nt < 8; ++nt){
        float m = fmaxf(rmax[nt], __shfl_xor(rmax[nt], 32));
        if (hi == 0){
            int e = nt*32 + lo;
            xc[((size_t)b*27 + SBASE + bin)*256 + e] = m + CB[e];
        }
    }
}

// grid: 216 blocks x 4 waves; each scale has 288 bin-tasks (32 b x 9 bins)
__global__ __launch_bounds__(256, 1) void k_conv_pool(
        const float* __restrict__ x0, const float* __restrict__ x1, const float* __restrict__ x2,
        const unsigned short* __restrict__ wt0, const unsigned short* __restrict__ wt1,
        const unsigned short* __restrict__ wt2,
        const float* __restrict__ cb0, const float* __restrict__ cb1, const float* __restrict__ cb2,
        float* __restrict__ xc){
    int blk = blockIdx.x, w = threadIdx.x >> 6;
    if (blk < 72){
        int task = blk * 4 + w;
        conv_bin<256, 48, 16, 0, 8>(x0, wt0, cb0, xc, task / 9, task % 9);
    } else if (blk < 144){
        int task = (blk - 72) * 4 + w;
        conv_bin<512, 24, 8, 9, 2>(x1, wt1, cb1, xc, task / 9, task % 9);
    } else {
        int task = (blk - 144) * 4 + w;
        conv_bin<1024, 12, 4, 18, 1>(x2, wt2, cb2, xc, task / 9, task % 9);
    }
}

// ---------------- q = LN(text) @ q_w + q_b  -> bf16 q[row][256] ----------------
__global__ __launch_bounds__(128) void k_qgemm(const unsigned short* __restrict__ lntext,
        const unsigned short* __restrict__ qwt, const float* __restrict__ qb,
        unsigned short* __restrict__ qout){
    int wave = threadIdx.x >> 6, lane = threadIdx.x & 63, lo = lane & 31, hi = lane >> 5;
    size_t row0 = (size_t)blockIdx.x * 64 + wave * 32;
    f32x16 acc[8];
#pragma unroll
    for (int nt = 0; nt < 8; ++nt) acc[nt] = zero16();
    const unsigned short* arow = lntext + (row0 + lo) * 512 + hi * 8;
    for (int ks = 0; ks < 32; ++ks){
        bf16x8 a = ld_bf16x8(arow + ks * 16);
#pragma unroll
        for (int nt = 0; nt < 8; ++nt){
            bf16x8 bfr = ld_bf16x8(qwt + (size_t)(nt*32 + lo) * 512 + ks*16 + hi*8);
            acc[nt] = mfma_bf16(a, bfr, acc[nt]);
        }
    }
#pragma unroll
    for (int nt = 0; nt < 8; ++nt){
        int e = nt * 32 + lo;
        float qbias = qb[e];
#pragma unroll
        for (int r = 0; r < 16; ++r){
            size_t row = row0 + (r & 3) + 8 * (r >> 2) + 4 * hi;
            qout[row * 256 + e] = f2b(acc[nt][r] + qbias);
        }
    }
}

// ---------------- k,v = LN(xc) @ {k_w,v_w} + bias ; 4 rows per block ----------------
__global__ __launch_bounds__(256) void k_kv(const float* __restrict__ xc,
        const float* __restrict__ kg, const float* __restrict__ kb,
        const float* __restrict__ vg, const float* __restrict__ vb,
        const float* __restrict__ k_w, const float* __restrict__ k_bias,
        const float* __restrict__ v_w, const float* __restrict__ v_bias,
        float* __restrict__ kout, float* __restrict__ vout){
    __shared__ float lnk[4][256];
    __shared__ float lnv[4][256];
    int w = threadIdx.x >> 6, lane = threadIdx.x & 63;
    size_t row = (size_t)blockIdx.x * 4 + w;
    f32x4 xv = *(const f32x4*)(xc + row * 256 + lane * 4);
    float s = xv[0]+xv[1]+xv[2]+xv[3];
#pragma unroll
    for (int off = 32; off; off >>= 1) s += __shfl_xor(s, off);
    float mean = s * (1.f/256.f);
    float d0 = xv[0]-mean, d1 = xv[1]-mean, d2 = xv[2]-mean, d3 = xv[3]-mean;
    float vs = d0*d0 + d1*d1 + d2*d2 + d3*d3;
#pragma unroll
    for (int off = 32; off; off >>= 1) vs += __shfl_xor(vs, off);
    float rstd = rsqrtf(vs * (1.f/256.f) + 1e-5f);
    int c0 = lane * 4;
#pragma unroll
    for (int j = 0; j < 4; ++j){
        float dd = xv[j] - mean;
        lnk[w][c0+j] = dd * rstd * kg[c0+j] + kb[c0+j];
        lnv[w][c0+j] = dd * rstd * vg[c0+j] + vb[c0+j];
    }
    __syncthreads();
    int t = threadIdx.x;
    float aK[4], aV[4];
#pragma unroll
    for (int r = 0; r < 4; ++r){ aK[r] = 0.f; aV[r] = 0.f; }
    for (int c = 0; c < 256; ++c){
        float wk = k_w[(size_t)c * 256 + t];
        float wv = v_w[(size_t)c * 256 + t];
#pragma unroll
        for (int r = 0; r < 4; ++r){
            aK[r] += lnk[r][c] * wk;
            aV[r] += lnv[r][c] * wv;
        }
    }
    float kbias = k_bias[t], vbias = v_bias[t];
    size_t base = (size_t)blockIdx.x * 4;
#pragma unroll
    for (int r = 0; r < 4; ++r){
        kout[(base + r) * 256 + t] = aK[r] + kbias;
        vout[(base + r) * 256 + t] = aV[r] + vbias;
    }
}

// ---------------- attention: block = (b, row-group of 32); lane owns 4 channels ----------------
__global__ __launch_bounds__(256, 2) void k_attn(const unsigned short* __restrict__ qbf,
        const float* __restrict__ kbuf, const float* __restrict__ vbuf,
        unsigned short* __restrict__ obf){
    int b = blockIdx.x >> 4;           // 32 batches
    int rg = blockIdx.x & 15;          // 16 row-groups of 32 rows
    __shared__ float ks_[27 * 256];
    __shared__ float vs_[27 * 256];
    {
        const f32x4* ksrc = (const f32x4*)(kbuf + (size_t)b * 27 * 256);
        const f32x4* vsrc = (const f32x4*)(vbuf + (size_t)b * 27 * 256);
        f32x4* kd = (f32x4*)ks_;
        f32x4* vd = (f32x4*)vs_;
        for (int i = threadIdx.x; i < 27 * 64; i += 256){ kd[i] = ksrc[i]; vd[i] = vsrc[i]; }
    }
    __syncthreads();
    int wave = threadIdx.x >> 6, lane = threadIdx.x & 63;
    int c0 = lane * 4;                 // 4 channels per lane; 256 channels per row
#pragma unroll
    for (int rr = 0; rr < 8; ++rr){
        int row = rg * 32 + wave * 8 + rr;
        const unsigned short* qp = qbf + ((size_t)b * 512 + row) * 256 + c0;
        us4 qu = *(const us4*)qp;
        float q0 = b2f(qu[0]), q1 = b2f(qu[1]), q2 = b2f(qu[2]), q3 = b2f(qu[3]);
        float sc[27]; float mx = -3.4e38f;
#pragma unroll
        for (int kk = 0; kk < 27; ++kk){
            f32x4 kv = *(const f32x4*)(ks_ + kk * 256 + c0);
            float s = q0*kv[0] + q1*kv[1] + q2*kv[2] + q3*kv[3];
            s += __shfl_xor(s, 1); s += __shfl_xor(s, 2); s += __shfl_xor(s, 4);
            s *= 0.17677669529663687f;            // 1/sqrt(32)
            sc[kk] = s; mx = fmaxf(mx, s);
        }
        float sum = 0.f;
#pragma unroll
        for (int kk = 0; kk < 27; ++kk){ float p = __expf(sc[kk] - mx); sc[kk] = p; sum += p; }
        float inv = 1.f / sum;
        float o0 = 0.f, o1 = 0.f, o2 = 0.f, o3 = 0.f;
#pragma unroll
        for (int kk = 0; kk < 27; ++kk){
            f32x4 vv = *(const f32x4*)(vs_ + kk * 256 + c0);
            float p = sc[kk];
            o0 += p*vv[0]; o1 += p*vv[1]; o2 += p*vv[2]; o3 += p*vv[3];
        }
        us4 ou;
        ou[0] = f2b(o0*inv); ou[1] = f2b(o1*inv); ou[2] = f2b(o2*inv); ou[3] = f2b(o3*inv);
        *(us4*)(obf + ((size_t)b * 512 + row) * 256 + c0) = ou;
    }
}

// ---------------- out = O @ proj_w + proj_b + text ----------------
__global__ __launch_bounds__(128) void k_proj(const unsigned short* __restrict__ obf,
        const unsigned short* __restrict__ pwt, const float* __restrict__ pb,
        const float* __restrict__ text, float* __restrict__ out){
    int wave = threadIdx.x >> 6, lane = threadIdx.x & 63, lo = lane & 31, hi = lane >> 5;
    size_t row0 = (size_t)(blockIdx.x >> 1) * 64 + wave * 32;
    int ct0 = (blockIdx.x & 1) * 256;
    f32x16 acc[8];
#pragma unroll
    for (int nt = 0; nt < 8; ++nt) acc[nt] = zero16();
    const unsigned short* arow = obf + (row0 + lo) * 256 + hi * 8;
    for (int ks = 0; ks < 16; ++ks){
        bf16x8 a = ld_bf16x8(arow + ks * 16);
#pragma unroll
        for (int nt = 0; nt < 8; ++nt){
            bf16x8 bfr = ld_bf16x8(pwt + (size_t)(ct0 + nt*32 + lo) * 256 + ks*16 + hi*8);
            acc[nt] = mfma_bf16(a, bfr, acc[nt]);
        }
    }
#pragma unroll
    for (int nt = 0; nt < 8; ++nt){
        int ct = ct0 + nt * 32 + lo;
        float pbias = pb[ct];
#pragma unroll
        for (int r = 0; r < 16; ++r){
            size_t row = row0 + (r & 3) + 8 * (r >> 2) + 4 * hi;
            out[row * 512 + ct] = acc[nt][r] + pbias + text[row * 512 + ct];
        }
    }
}

extern "C" void kernel_launch(void* const* d_in, const int* in_sizes, int n_in,
                              void* d_out, int out_size, void* d_ws, size_t ws_size,
                              hipStream_t stream) {
    (void)in_sizes; (void)n_in; (void)out_size; (void)ws_size;
    const float* x0     = (const float*)d_in[0];
    const float* x1     = (const float*)d_in[1];
    const float* x2     = (const float*)d_in[2];
    const float* text   = (const float*)d_in[3];
    const float* w0     = (const float*)d_in[4];
    const float* cb0    = (const float*)d_in[5];
    const float* w1     = (const float*)d_in[6];
    const float* cb1    = (const float*)d_in[7];
    const float* w2     = (const float*)d_in[8];
    const float* cb2    = (const float*)d_in[9];
    const float* q_ln_g = (const float*)d_in[10];
    const float* q_ln_b = (const float*)d_in[11];
    const float* k_ln_g = (const float*)d_in[12];
    const float* k_ln_b = (const float*)d_in[13];
    const float* v_ln_g = (const float*)d_in[14];
    const float* v_ln_b = (const float*)d_in[15];
    const float* q_w    = (const float*)d_in[16];
    const float* q_b    = (const float*)d_in[17];
    const float* k_w    = (const float*)d_in[18];
    const float* k_b    = (const float*)d_in[19];
    const float* v_w    = (const float*)d_in[20];
    const float* v_b    = (const float*)d_in[21];
    const float* proj_w = (const float*)d_in[22];
    const float* proj_b = (const float*)d_in[23];
    float* out = (float*)d_out;

    char* wsb = (char*)d_ws; size_t off = 0;
    auto take = [&](size_t bytes) -> void* {
        void* p = wsb + off; off += (bytes + 255) & ~(size_t)255; return p;
    };
    unsigned short* lntext = (unsigned short*)take((size_t)16384 * 512 * 2);
    unsigned short* qbf    = (unsigned short*)take((size_t)16384 * 256 * 2);
    unsigned short* obf    = (unsigned short*)take((size_t)16384 * 256 * 2);
    float*          xc     = (float*)take((size_t)32 * 27 * 256 * 4);
    float*          kbuf   = (float*)take((size_t)32 * 27 * 256 * 4);
    float*          vbuf   = (float*)take((size_t)32 * 27 * 256 * 4);
    unsigned short* wt0    = (unsigned short*)take((size_t)256 * 256 * 2);
    unsigned short* wt1    = (unsigned short*)take((size_t)256 * 512 * 2);
    unsigned short* wt2    = (unsigned short*)take((size_t)256 * 1024 * 2);
    unsigned short* qwt    = (unsigned short*)take((size_t)256 * 512 * 2);
    unsigned short* pwt    = (unsigned short*)take((size_t)512 * 256 * 2);

    k_transpose_bf16<<<(256*256 + 255) / 256, 256, 0, stream>>>(w0, wt0, 256, 256);
    k_transpose_bf16<<<(512*256 + 255) / 256, 256, 0, stream>>>(w1, wt1, 512, 256);
    k_transpose_bf16<<<(1024*256 + 255) / 256, 256, 0, stream>>>(w2, wt2, 1024, 256);
    k_transpose_bf16<<<(512*256 + 255) / 256, 256, 0, stream>>>(q_w, qwt, 512, 256);
    k_transpose_bf16<<<(256*512 + 255) / 256, 256, 0, stream>>>(proj_w, pwt, 256, 512);

    k_ln_text<<<4096, 256, 0, stream>>>(text, q_ln_g, q_ln_b, lntext);
    k_conv_pool<<<216, 256, 0, stream>>>(x0, x1, x2, wt0, wt1, wt2, cb0, cb1, cb2, xc);
    k_qgemm<<<256, 128, 0, stream>>>(lntext, qwt, q_b, qbf);
    k_kv<<<216, 256, 0, stream>>>(xc, k_ln_g, k_ln_b, v_ln_g, v_ln_b,
                                  k_w, k_b, v_w, v_b, kbuf, vbuf);
    k_attn<<<512, 256, 0, stream>>>(qbf, kbuf, vbuf, obf);
    k_proj<<<512, 128, 0, stream>>>(obf, pwt, proj_b, text, out);
}

// Round 6
// 368.227 us; speedup vs baseline: 3.5294x; 1.0019x over previous
//
#include <hip/hip_runtime.h>
#include <stdint.h>

#define DEVFN __device__ __forceinline__

using f32x4   = __attribute__((ext_vector_type(4)))  float;
using f32x16  = __attribute__((ext_vector_type(16))) float;
using us4     = __attribute__((ext_vector_type(4)))  unsigned short;
using us8     = __attribute__((ext_vector_type(8)))  unsigned short;
using bf16x8  = __attribute__((ext_vector_type(8)))  __bf16;

DEVFN unsigned short f2b(float x){
    union { float f; unsigned u; } v; v.f = x;
    unsigned r = v.u + 0x7FFFu + ((v.u >> 16) & 1u);   // RNE
    return (unsigned short)(r >> 16);
}
DEVFN float b2f(unsigned short u){
    union { unsigned u; float f; } v; v.u = ((unsigned)u) << 16; return v.f;
}
DEVFN bf16x8 ld_bf16x8(const unsigned short* p){
    return __builtin_bit_cast(bf16x8, *(const us8*)p);
}
DEVFN bf16x8 pack_bf16x8(const float* f){
    us8 u;
#pragma unroll
    for (int j = 0; j < 8; ++j) u[j] = f2b(f[j]);
    return __builtin_bit_cast(bf16x8, u);
}
DEVFN f32x16 zero16(){
    f32x16 z;
#pragma unroll
    for (int i = 0; i < 16; ++i) z[i] = 0.f;
    return z;
}
DEVFN f32x16 mfma_bf16(bf16x8 a, bf16x8 b, f32x16 c){
    return __builtin_amdgcn_mfma_f32_32x32x16_bf16(a, b, c, 0, 0, 0);
}

// ---------------- transpose weight [R][Cc] f32 -> [Cc][R] bf16 ----------------
__global__ void k_transpose_bf16(const float* __restrict__ in, unsigned short* __restrict__ out,
                                 int R, int Cc){
    int idx = blockIdx.x * 256 + threadIdx.x;
    if (idx >= R * Cc) return;
    int i = idx / R, j = idx % R;          // out[i][j] = in[j][i]
    out[idx] = f2b(in[(size_t)j * Cc + i]);
}

// ---------------- LN(text) -> bf16 ; one wave per row of 512 ----------------
__global__ __launch_bounds__(256) void k_ln_text(const float* __restrict__ text,
        const float* __restrict__ g, const float* __restrict__ bb,
        unsigned short* __restrict__ out){
    int wave = threadIdx.x >> 6, lane = threadIdx.x & 63;
    size_t row = (size_t)blockIdx.x * 4 + wave;        // 16384 rows
    const float* p = text + row * 512 + lane * 8;
    f32x4 a = *(const f32x4*)p;
    f32x4 c = *(const f32x4*)(p + 4);
    float s = a[0]+a[1]+a[2]+a[3]+c[0]+c[1]+c[2]+c[3];
#pragma unroll
    for (int off = 32; off; off >>= 1) s += __shfl_xor(s, off);
    float mean = s * (1.f/512.f);
    float d[8];
    d[0]=a[0]-mean; d[1]=a[1]-mean; d[2]=a[2]-mean; d[3]=a[3]-mean;
    d[4]=c[0]-mean; d[5]=c[1]-mean; d[6]=c[2]-mean; d[7]=c[3]-mean;
    float vs = d[0]*d[0]+d[1]*d[1]+d[2]*d[2]+d[3]*d[3]+d[4]*d[4]+d[5]*d[5]+d[6]*d[6]+d[7]*d[7];
#pragma unroll
    for (int off = 32; off; off >>= 1) vs += __shfl_xor(vs, off);
    float rstd = rsqrtf(vs * (1.f/512.f) + 1e-5f);
    const float* gp = g  + lane * 8;
    const float* bp = bb + lane * 8;
    f32x4 g0 = *(const f32x4*)gp, g1 = *(const f32x4*)(gp+4);
    f32x4 b0 = *(const f32x4*)bp, b1 = *(const f32x4*)(bp+4);
    us8 o;
#pragma unroll
    for (int j = 0; j < 4; ++j) o[j]   = f2b(d[j]  *rstd*g0[j] + b0[j]);
#pragma unroll
    for (int j = 0; j < 4; ++j) o[4+j] = f2b(d[4+j]*rstd*g1[j] + b1[j]);
    *(us8*)(out + row * 512 + lane * 8) = o;
}

// ---------------- fused 1x1-conv + adaptive max pool -> xc[b][27][256] ----------------
// One wave computes ONE 32-pixel sub-tile of a bin vs all 256 e-channels,
// folding the D-rows into rmax[8]; sub-tiles of a bin are spread across the
// block's waves and combined with a tiny LDS max-reduce (no races).
// A-loads double-buffered (prefetch k+1 under k's MFMAs); W frags transient.
template<int C, int WIMG, int BINW>
DEVFN void conv_sub(const float* __restrict__ X, const unsigned short* __restrict__ WT,
                    int b, int bin, int sub, float* rmax){
    const int HW = WIMG * WIMG;
    int lane = threadIdx.x & 63, lo = lane & 31, hi = lane >> 5;
    int binr = bin / 3, binc = bin % 3;
    int prow, pcol;
    if constexpr (BINW == 16){ prow = sub*2 + (lo>>4); pcol = lo & 15; }
    else if constexpr (BINW == 8){ prow = sub*4 + (lo>>3); pcol = lo & 7; }
    else { prow = (lo & 15) >> 2; pcol = lo & 3; }     // 16 px duplicated x2
    int gr = binr * BINW + prow, gc = binc * BINW + pcol;
    const float* Xp = X + (size_t)b * C * HW + gr * WIMG + gc;
    const unsigned short* wbase = WT + (size_t)lo * C + hi * 8;

    f32x16 acc[8];
#pragma unroll
    for (int nt = 0; nt < 8; ++nt) acc[nt] = zero16();

    const int NK = C / 16;
    float cur[8], nxt[8];
    {
        const float* ap = Xp + (size_t)(hi*8) * HW;
#pragma unroll
        for (int j = 0; j < 8; ++j) cur[j] = ap[(size_t)j * HW];
    }
    for (int ks = 0; ks < NK; ++ks){
        if (ks + 1 < NK){
            const float* ap = Xp + (size_t)((ks+1)*16 + hi*8) * HW;
#pragma unroll
            for (int j = 0; j < 8; ++j) nxt[j] = ap[(size_t)j * HW];
        }
        bf16x8 A = pack_bf16x8(cur);
#pragma unroll
        for (int nt = 0; nt < 8; ++nt){
            bf16x8 B = ld_bf16x8(wbase + (size_t)nt*32*C + ks*16);
            acc[nt] = mfma_bf16(A, B, acc[nt]);
        }
        if (ks + 1 < NK){
#pragma unroll
            for (int j = 0; j < 8; ++j) cur[j] = nxt[j];
        }
    }
#pragma unroll
    for (int nt = 0; nt < 8; ++nt){
        float m = acc[nt][0];
#pragma unroll
        for (int r = 1; r < 16; ++r) m = fmaxf(m, acc[nt][r]);
        rmax[nt] = fmaxf(rmax[nt], m);
    }
}

// grid: 288 (s0: b x bin) + 160 (s1: b x bin-pair) + 96 (s2: b x bin-quad) = 544
__global__ __launch_bounds__(256, 2) void k_conv_pool(
        const float* __restrict__ x0, const float* __restrict__ x1, const float* __restrict__ x2,
        const unsigned short* __restrict__ wt0, const unsigned short* __restrict__ wt1,
        const unsigned short* __restrict__ wt2,
        const float* __restrict__ cb0, const float* __restrict__ cb1, const float* __restrict__ cb2,
        float* __restrict__ xc){
    __shared__ float red[4][8][32];
    int blk = blockIdx.x, w = threadIdx.x >> 6, lane = threadIdx.x & 63;
    int lo = lane & 31, hi = lane >> 5;
    float rmax[8];
#pragma unroll
    for (int nt = 0; nt < 8; ++nt) rmax[nt] = -3.4e38f;

    if (blk < 288){                       // ---- scale 0: wave w does subs w, w+4
        int b = blk / 9, bin = blk % 9;
        conv_sub<256, 48, 16>(x0, wt0, b, bin, w,     rmax);
        conv_sub<256, 48, 16>(x0, wt0, b, bin, w + 4, rmax);
#pragma unroll
        for (int nt = 0; nt < 8; ++nt){
            float m = fmaxf(rmax[nt], __shfl_xor(rmax[nt], 32));
            if (hi == 0) red[w][nt][lo] = m;
        }
        __syncthreads();
        int t = threadIdx.x, nt = t >> 5, l = t & 31, e = nt*32 + l;
        float m = fmaxf(fmaxf(red[0][nt][l], red[1][nt][l]),
                        fmaxf(red[2][nt][l], red[3][nt][l]));
        xc[((size_t)b*27 + bin)*256 + e] = m + cb0[e];
    } else if (blk < 448){                // ---- scale 1: waves 0,1 -> binA; 2,3 -> binB
        int r = blk - 288, b = r / 5, p = r % 5;
        int binA = 2*p;
        bool hasB = (2*p + 1 <= 8);
        int binB = hasB ? 2*p + 1 : binA;
        int bin = (w < 2) ? binA : binB;
        conv_sub<512, 24, 8>(x1, wt1, b, bin, w & 1, rmax);
#pragma unroll
        for (int nt = 0; nt < 8; ++nt){
            float m = fmaxf(rmax[nt], __shfl_xor(rmax[nt], 32));
            if (hi == 0) red[w][nt][lo] = m;
        }
        __syncthreads();
        int t = threadIdx.x, nt = t >> 5, l = t & 31, e = nt*32 + l;
        float mA = fmaxf(red[0][nt][l], red[1][nt][l]);
        xc[((size_t)b*27 + 9 + binA)*256 + e] = mA + cb1[e];
        if (hasB){
            float mB = fmaxf(red[2][nt][l], red[3][nt][l]);
            xc[((size_t)b*27 + 9 + binB)*256 + e] = mB + cb1[e];
        }
    } else {                              // ---- scale 2: one wave per bin, direct write
        int r = blk - 448, b = r / 3, q = r % 3;
        int bin = q*4 + w;
        if (bin <= 8){
            conv_sub<1024, 12, 4>(x2, wt2, b, bin, 0, rmax);
#pragma unroll
            for (int nt = 0; nt < 8; ++nt){
                float m = fmaxf(rmax[nt], __shfl_xor(rmax[nt], 32));
                if (hi == 0){
                    int e = nt*32 + lo;
                    xc[((size_t)b*27 + 18 + bin)*256 + e] = m + cb2[e];
                }
            }
        }
    }
}

// ---------------- q = LN(text) @ q_w + q_b  -> bf16 q[row][256] ----------------
__global__ __launch_bounds__(128) void k_qgemm(const unsigned short* __restrict__ lntext,
        const unsigned short* __restrict__ qwt, const float* __restrict__ qb,
        unsigned short* __restrict__ qout){
    int wave = threadIdx.x >> 6, lane = threadIdx.x & 63, lo = lane & 31, hi = lane >> 5;
    size_t row0 = (size_t)blockIdx.x * 64 + wave * 32;
    f32x16 acc[8];
#pragma unroll
    for (int nt = 0; nt < 8; ++nt) acc[nt] = zero16();
    const unsigned short* arow = lntext + (row0 + lo) * 512 + hi * 8;
    for (int ks = 0; ks < 32; ++ks){
        bf16x8 a = ld_bf16x8(arow + ks * 16);
#pragma unroll
        for (int nt = 0; nt < 8; ++nt){
            bf16x8 bfr = ld_bf16x8(qwt + (size_t)(nt*32 + lo) * 512 + ks*16 + hi*8);
            acc[nt] = mfma_bf16(a, bfr, acc[nt]);
        }
    }
#pragma unroll
    for (int nt = 0; nt < 8; ++nt){
        int e = nt * 32 + lo;
        float qbias = qb[e];
#pragma unroll
        for (int r = 0; r < 16; ++r){
            size_t row = row0 + (r & 3) + 8 * (r >> 2) + 4 * hi;
            qout[row * 256 + e] = f2b(acc[nt][r] + qbias);
        }
    }
}

// ---------------- k,v = LN(xc) @ {k_w,v_w} + bias ; 4 rows per block ----------------
__global__ __launch_bounds__(256) void k_kv(const float* __restrict__ xc,
        const float* __restrict__ kg, const float* __restrict__ kb,
        const float* __restrict__ vg, const float* __restrict__ vb,
        const float* __restrict__ k_w, const float* __restrict__ k_bias,
        const float* __restrict__ v_w, const float* __restrict__ v_bias,
        float* __restrict__ kout, float* __restrict__ vout){
    __shared__ float lnk[4][256];
    __shared__ float lnv[4][256];
    int w = threadIdx.x >> 6, lane = threadIdx.x & 63;
    size_t row = (size_t)blockIdx.x * 4 + w;
    f32x4 xv = *(const f32x4*)(xc + row * 256 + lane * 4);
    float s = xv[0]+xv[1]+xv[2]+xv[3];
#pragma unroll
    for (int off = 32; off; off >>= 1) s += __shfl_xor(s, off);
    float mean = s * (1.f/256.f);
    float d0 = xv[0]-mean, d1 = xv[1]-mean, d2 = xv[2]-mean, d3 = xv[3]-mean;
    float vs = d0*d0 + d1*d1 + d2*d2 + d3*d3;
#pragma unroll
    for (int off = 32; off; off >>= 1) vs += __shfl_xor(vs, off);
    float rstd = rsqrtf(vs * (1.f/256.f) + 1e-5f);
    int c0 = lane * 4;
#pragma unroll
    for (int j = 0; j < 4; ++j){
        float dd = xv[j] - mean;
        lnk[w][c0+j] = dd * rstd * kg[c0+j] + kb[c0+j];
        lnv[w][c0+j] = dd * rstd * vg[c0+j] + vb[c0+j];
    }
    __syncthreads();
    int t = threadIdx.x;
    float aK[4], aV[4];
#pragma unroll
    for (int r = 0; r < 4; ++r){ aK[r] = 0.f; aV[r] = 0.f; }
    for (int c = 0; c < 256; ++c){
        float wk = k_w[(size_t)c * 256 + t];
        float wv = v_w[(size_t)c * 256 + t];
#pragma unroll
        for (int r = 0; r < 4; ++r){
            aK[r] += lnk[r][c] * wk;
            aV[r] += lnv[r][c] * wv;
        }
    }
    float kbias = k_bias[t], vbias = v_bias[t];
    size_t base = (size_t)blockIdx.x * 4;
#pragma unroll
    for (int r = 0; r < 4; ++r){
        kout[(base + r) * 256 + t] = aK[r] + kbias;
        vout[(base + r) * 256 + t] = aV[r] + vbias;
    }
}

// ---------------- attention: block = (b, row-group of 32); lane owns 4 channels ----------------
__global__ __launch_bounds__(256, 2) void k_attn(const unsigned short* __restrict__ qbf,
        const float* __restrict__ kbuf, const float* __restrict__ vbuf,
        unsigned short* __restrict__ obf){
    int b = blockIdx.x >> 4;           // 32 batches
    int rg = blockIdx.x & 15;          // 16 row-groups of 32 rows
    __shared__ float ks_[27 * 256];
    __shared__ float vs_[27 * 256];
    {
        const f32x4* ksrc = (const f32x4*)(kbuf + (size_t)b * 27 * 256);
        const f32x4* vsrc = (const f32x4*)(vbuf + (size_t)b * 27 * 256);
        f32x4* kd = (f32x4*)ks_;
        f32x4* vd = (f32x4*)vs_;
        for (int i = threadIdx.x; i < 27 * 64; i += 256){ kd[i] = ksrc[i]; vd[i] = vsrc[i]; }
    }
    __syncthreads();
    int wave = threadIdx.x >> 6, lane = threadIdx.x & 63;
    int c0 = lane * 4;                 // 4 channels per lane; 256 channels per row
#pragma unroll
    for (int rr = 0; rr < 8; ++rr){
        int row = rg * 32 + wave * 8 + rr;
        const unsigned short* qp = qbf + ((size_t)b * 512 + row) * 256 + c0;
        us4 qu = *(const us4*)qp;
        float q0 = b2f(qu[0]), q1 = b2f(qu[1]), q2 = b2f(qu[2]), q3 = b2f(qu[3]);
        float sc[27]; float mx = -3.4e38f;
#pragma unroll
        for (int kk = 0; kk < 27; ++kk){
            f32x4 kv = *(const f32x4*)(ks_ + kk * 256 + c0);
            float s = q0*kv[0] + q1*kv[1] + q2*kv[2] + q3*kv[3];
            s += __shfl_xor(s, 1); s += __shfl_xor(s, 2); s += __shfl_xor(s, 4);
            s *= 0.17677669529663687f;            // 1/sqrt(32)
            sc[kk] = s; mx = fmaxf(mx, s);
        }
        float sum = 0.f;
#pragma unroll
        for (int kk = 0; kk < 27; ++kk){ float p = __expf(sc[kk] - mx); sc[kk] = p; sum += p; }
        float inv = 1.f / sum;
        float o0 = 0.f, o1 = 0.f, o2 = 0.f, o3 = 0.f;
#pragma unroll
        for (int kk = 0; kk < 27; ++kk){
            f32x4 vv = *(const f32x4*)(vs_ + kk * 256 + c0);
            float p = sc[kk];
            o0 += p*vv[0]; o1 += p*vv[1]; o2 += p*vv[2]; o3 += p*vv[3];
        }
        us4 ou;
        ou[0] = f2b(o0*inv); ou[1] = f2b(o1*inv); ou[2] = f2b(o2*inv); ou[3] = f2b(o3*inv);
        *(us4*)(obf + ((size_t)b * 512 + row) * 256 + c0) = ou;
    }
}

// ---------------- out = O @ proj_w + proj_b + text ----------------
__global__ __launch_bounds__(128) void k_proj(const unsigned short* __restrict__ obf,
        const unsigned short* __restrict__ pwt, const float* __restrict__ pb,
        const float* __restrict__ text, float* __restrict__ out){
    int wave = threadIdx.x >> 6, lane = threadIdx.x & 63, lo = lane & 31, hi = lane >> 5;
    size_t row0 = (size_t)(blockIdx.x >> 1) * 64 + wave * 32;
    int ct0 = (blockIdx.x & 1) * 256;
    f32x16 acc[8];
#pragma unroll
    for (int nt = 0; nt < 8; ++nt) acc[nt] = zero16();
    const unsigned short* arow = obf + (row0 + lo) * 256 + hi * 8;
    for (int ks = 0; ks < 16; ++ks){
        bf16x8 a = ld_bf16x8(arow + ks * 16);
#pragma unroll
        for (int nt = 0; nt < 8; ++nt){
            bf16x8 bfr = ld_bf16x8(pwt + (size_t)(ct0 + nt*32 + lo) * 256 + ks*16 + hi*8);
            acc[nt] = mfma_bf16(a, bfr, acc[nt]);
        }
    }
#pragma unroll
    for (int nt = 0; nt < 8; ++nt){
        int ct = ct0 + nt * 32 + lo;
        float pbias = pb[ct];
#pragma unroll
        for (int r = 0; r < 16; ++r){
            size_t row = row0 + (r & 3) + 8 * (r >> 2) + 4 * hi;
            out[row * 512 + ct] = acc[nt][r] + pbias + text[row * 512 + ct];
        }
    }
}

extern "C" void kernel_launch(void* const* d_in, const int* in_sizes, int n_in,
                              void* d_out, int out_size, void* d_ws, size_t ws_size,
                              hipStream_t stream) {
    (void)in_sizes; (void)n_in; (void)out_size; (void)ws_size;
    const float* x0     = (const float*)d_in[0];
    const float* x1     = (const float*)d_in[1];
    const float* x2     = (const float*)d_in[2];
    const float* text   = (const float*)d_in[3];
    const float* w0     = (const float*)d_in[4];
    const float* cb0    = (const float*)d_in[5];
    const float* w1     = (const float*)d_in[6];
    const float* cb1    = (const float*)d_in[7];
    const float* w2     = (const float*)d_in[8];
    const float* cb2    = (const float*)d_in[9];
    const float* q_ln_g = (const float*)d_in[10];
    const float* q_ln_b = (const float*)d_in[11];
    const float* k_ln_g = (const float*)d_in[12];
    const float* k_ln_b = (const float*)d_in[13];
    const float* v_ln_g = (const float*)d_in[14];
    const float* v_ln_b = (const float*)d_in[15];
    const float* q_w    = (const float*)d_in[16];
    const float* q_b    = (const float*)d_in[17];
    const float* k_w    = (const float*)d_in[18];
    const float* k_b    = (const float*)d_in[19];
    const float* v_w    = (const float*)d_in[20];
    const float* v_b    = (const float*)d_in[21];
    const float* proj_w = (const float*)d_in[22];
    const float* proj_b = (const float*)d_in[23];
    float* out = (float*)d_out;

    char* wsb = (char*)d_ws; size_t off = 0;
    auto take = [&](size_t bytes) -> void* {
        void* p = wsb + off; off += (bytes + 255) & ~(size_t)255; return p;
    };
    unsigned short* lntext = (unsigned short*)take((size_t)16384 * 512 * 2);
    unsigned short* qbf    = (unsigned short*)take((size_t)16384 * 256 * 2);
    unsigned short* obf    = (unsigned short*)take((size_t)16384 * 256 * 2);
    float*          xc     = (float*)take((size_t)32 * 27 * 256 * 4);
    float*          kbuf   = (float*)take((size_t)32 * 27 * 256 * 4);
    float*          vbuf   = (float*)take((size_t)32 * 27 * 256 * 4);
    unsigned short* wt0    = (unsigned short*)take((size_t)256 * 256 * 2);
    unsigned short* wt1    = (unsigned short*)take((size_t)256 * 512 * 2);
    unsigned short* wt2    = (unsigned short*)take((size_t)256 * 1024 * 2);
    unsigned short* qwt    = (unsigned short*)take((size_t)256 * 512 * 2);
    unsigned short* pwt    = (unsigned short*)take((size_t)512 * 256 * 2);

    k_transpose_bf16<<<(256*256 + 255) / 256, 256, 0, stream>>>(w0, wt0, 256, 256);
    k_transpose_bf16<<<(512*256 + 255) / 256, 256, 0, stream>>>(w1, wt1, 512, 256);
    k_transpose_bf16<<<(1024*256 + 255) / 256, 256, 0, stream>>>(w2, wt2, 1024, 256);
    k_transpose_bf16<<<(512*256 + 255) / 256, 256, 0, stream>>>(q_w, qwt, 512, 256);
    k_transpose_bf16<<<(256*512 + 255) / 256, 256, 0, stream>>>(proj_w, pwt, 256, 512);

    k_ln_text<<<4096, 256, 0, stream>>>(text, q_ln_g, q_ln_b, lntext);
    k_conv_pool<<<544, 256, 0, stream>>>(x0, x1, x2, wt0, wt1, wt2, cb0, cb1, cb2, xc);
    k_qgemm<<<256, 128, 0, stream>>>(lntext, qwt, q_b, qbf);
    k_kv<<<216, 256, 0, stream>>>(xc, k_ln_g, k_ln_b, v_ln_g, v_ln_b,
                                  k_w, k_b, v_w, v_b, kbuf, vbuf);
    k_attn<<<512, 256, 0, stream>>>(qbf, kbuf, vbuf, obf);
    k_proj<<<512, 128, 0, stream>>>(obf, pwt, proj_b, text, out);
}